// Round 7
// baseline (258.102 us; speedup 1.0000x reference)
//
#include <hip/hip_runtime.h>
#include <hip/hip_bf16.h>
#include <math.h>

// Fused self-attention, B=8, S=2048, D=64 fp32; outputs context [8,2048,64] and
// full attention filter [8,2048,2048].
//
// Round-7: LDS-free K/V. With bf16 K in [b][s][d] and V pre-transposed to
// [b][d][s], the MFMA B-fragments for both QK^T and PV are 8 CONTIGUOUS bf16
// -> direct global bf16x8 loads (L2-resident: 256 KB K + 256 KB VT per batch).
// Eliminates all K/V LDS staging and every __syncthreads in the K-loops; LDS
// remains only for the per-wave P C->A bounce (same-wave, barrier-free).
// KSPLIT 4->8 (2048 WGs, BPW=4).

typedef short bf16x8 __attribute__((ext_vector_type(8)));
typedef short bf16x4 __attribute__((ext_vector_type(4)));
typedef float f32x4 __attribute__((ext_vector_type(4)));

#define BATCH 8
#define SDIM 2048
#define DDIM 64
#define KBLK 64
#define NBLK (SDIM / KBLK)      // 32
#define KSPLIT 8
#define BPW (NBLK / KSPLIT)     // 4 key-blocks per WG
#define NROWS (BATCH * SDIM)    // 16384
#define SCALE 0.125f
#define KSTR 72                 // Plds row stride in shorts (144 B, 16B-aligned)

__device__ __forceinline__ short f2bf(float f) {
    unsigned x = __float_as_uint(f);
    x = (x + 0x7fffu + ((x >> 16) & 1u)) >> 16;   // RNE
    return (short)x;
}
__device__ __forceinline__ float fidx(const float4& v, int i) {
    return ((const float*)&v)[i];
}

// ======== K0: K->bf16, V->bf16 transposed, zero Ctx.  256 WGs ========
__global__ __launch_bounds__(256, 4)
void attn_prep(const float* __restrict__ Kg, const float* __restrict__ Vg,
               short* __restrict__ Kbf, short* __restrict__ VTbf,
               float* __restrict__ Ctx)
{
    __shared__ short VTlds[DDIM][KSTR];

    const int wg = blockIdx.x;           // 256 = 8 batches x 32 key-blocks
    const int b = wg & 7;
    const int kbase = (wg >> 3) * KBLK;
    const int tid = threadIdx.x;

    const float* Kb = Kg + (size_t)b * SDIM * DDIM;
    const float* Vb = Vg + (size_t)b * SDIM * DDIM;

    // K convert: thread t -> key=t>>2, 16 d's
    {
        const int key = tid >> 2, doff = (tid & 3) * 16;
        const float* src = Kb + (size_t)(kbase + key) * DDIM + doff;
        float4 f0 = *(const float4*)(src);
        float4 f1 = *(const float4*)(src + 4);
        float4 f2 = *(const float4*)(src + 8);
        float4 f3 = *(const float4*)(src + 12);
        bf16x8 p0, p1;
        p0[0]=f2bf(f0.x); p0[1]=f2bf(f0.y); p0[2]=f2bf(f0.z); p0[3]=f2bf(f0.w);
        p0[4]=f2bf(f1.x); p0[5]=f2bf(f1.y); p0[6]=f2bf(f1.z); p0[7]=f2bf(f1.w);
        p1[0]=f2bf(f2.x); p1[1]=f2bf(f2.y); p1[2]=f2bf(f2.z); p1[3]=f2bf(f2.w);
        p1[4]=f2bf(f3.x); p1[5]=f2bf(f3.y); p1[6]=f2bf(f3.z); p1[7]=f2bf(f3.w);
        short* dst = Kbf + ((size_t)b * SDIM + kbase + key) * DDIM + doff;
        *(bf16x8*)dst = p0;
        *(bf16x8*)(dst + 8) = p1;
    }

    // V transpose via LDS: thread t loads 4 keys x 4 d's, writes transposed
    {
        const int sv_d0 = (tid & 15) * 4, sv_k0 = (tid >> 4) * 4;
        float4 vreg[4];
        #pragma unroll
        for (int i = 0; i < 4; ++i)
            vreg[i] = *(const float4*)(Vb + (size_t)(kbase + sv_k0 + i) * DDIM + sv_d0);
        #pragma unroll
        for (int dd = 0; dd < 4; ++dd) {
            bf16x4 pv;
            pv[0] = f2bf(fidx(vreg[0], dd));
            pv[1] = f2bf(fidx(vreg[1], dd));
            pv[2] = f2bf(fidx(vreg[2], dd));
            pv[3] = f2bf(fidx(vreg[3], dd));
            *(bf16x4*)&VTlds[sv_d0 + dd][sv_k0] = pv;
        }
    }
    __syncthreads();
    {
        const int d = tid >> 2, koff = (tid & 3) * 16;
        bf16x8 a = *(const bf16x8*)&VTlds[d][koff];
        bf16x8 c = *(const bf16x8*)&VTlds[d][koff + 8];
        short* dst = VTbf + ((size_t)b * DDIM + d) * SDIM + kbase + koff;
        *(bf16x8*)dst = a;
        *(bf16x8*)(dst + 8) = c;
    }

    // zero this WG's 16 KB slice of Ctx (4 MB / 256 WGs)
    {
        float4* dst = (float4*)Ctx + (size_t)wg * 1024;
        for (int i = tid; i < 1024; i += 256) dst[i] = make_float4(0.f, 0.f, 0.f, 0.f);
    }
}

// ============ K1: partial row sums — barrier-free, LDS-free ============
__global__ __launch_bounds__(256, 8)
void attn_stats(const short* __restrict__ Kbf, const float* __restrict__ Qg,
                const int* __restrict__ Mg, float* __restrict__ part)
{
    const int wg = blockIdx.x;           // 2048 = 8 b x 32 qt x 8 sp
    const int b = wg & 7;
    const int qt = (wg >> 3) & 31;
    const int sp = wg >> 8;
    const int tid = threadIdx.x;
    const int w = tid >> 6, lane = tid & 63, col = lane & 15, quad = lane >> 4;

    const float* Qb = Qg + (size_t)b * SDIM * DDIM;
    const int*   Mb = Mg + (size_t)b * SDIM;
    const short* Kb = Kbf + (size_t)b * SDIM * DDIM;

    // persistent Q A-fragments: A[m=col][k=quad*8+j], two 32-wide K chunks
    bf16x8 aq[2];
    {
        const float* qsrc = Qb + (size_t)(qt * 64 + w * 16 + col) * DDIM + quad * 8;
        #pragma unroll
        for (int c = 0; c < 2; ++c) {
            float4 f0 = *(const float4*)(qsrc + c * 32);
            float4 f1 = *(const float4*)(qsrc + c * 32 + 4);
            bf16x8 a;
            a[0]=f2bf(f0.x); a[1]=f2bf(f0.y); a[2]=f2bf(f0.z); a[3]=f2bf(f0.w);
            a[4]=f2bf(f1.x); a[5]=f2bf(f1.y); a[6]=f2bf(f1.z); a[7]=f2bf(f1.w);
            aq[c] = a;
        }
    }

    const int kb0 = sp * BPW * KBLK;
    float lsum[4];
    #pragma unroll
    for (int r = 0; r < 4; ++r) lsum[r] = 0.0f;

    for (int kb = 0; kb < BPW; ++kb) {
        const int kbase = kb0 + kb * KBLK;
        #pragma unroll
        for (int t = 0; t < 4; ++t) {
            // B-frag = K[key=kbase+t*16+col][d=c*32+quad*8 ..+7] — contiguous
            const short* krow = Kb + (size_t)(kbase + t * 16 + col) * DDIM + quad * 8;
            f32x4 acc = {0.f, 0.f, 0.f, 0.f};
            #pragma unroll
            for (int c = 0; c < 2; ++c) {
                bf16x8 bk = *(const bf16x8*)(krow + c * 32);
                acc = __builtin_amdgcn_mfma_f32_16x16x32_bf16(aq[c], bk, acc, 0, 0, 0);
            }
            const int mk = Mb[kbase + t * 16 + col];
            #pragma unroll
            for (int r = 0; r < 4; ++r)
                lsum[r] += mk ? 0.0f : __expf(acc[r] * SCALE);
        }
    }

    #pragma unroll
    for (int r = 0; r < 4; ++r) {
        float s = lsum[r];
        s += __shfl_xor(s, 1);
        s += __shfl_xor(s, 2);
        s += __shfl_xor(s, 4);
        s += __shfl_xor(s, 8);
        lsum[r] = s;
    }
    if (col == 0) {
        #pragma unroll
        for (int r = 0; r < 4; ++r)
            part[(size_t)sp * NROWS + b * SDIM + qt * 64 + w * 16 + quad * 4 + r] = lsum[r];
    }
}

// ===================== K2: merge partials -> 1/l =====================
__global__ __launch_bounds__(256)
void attn_merge(const float* __restrict__ part, float* __restrict__ stats)
{
    const int t = blockIdx.x * 256 + threadIdx.x;
    if (t < NROWS) {
        float l = 0.f;
        #pragma unroll
        for (int sp = 0; sp < KSPLIT; ++sp) l += part[(size_t)sp * NROWS + t];
        stats[t] = 1.0f / l;
    }
}

// ========= K3: emit filter + context — barrier-free, P-bounce only =========
__global__ __launch_bounds__(256, 6)
void attn_emit(const short* __restrict__ Kbf, const short* __restrict__ VTbf,
               const float* __restrict__ Qg, const int* __restrict__ Mg,
               const float* __restrict__ stats, float* __restrict__ Ctx,
               float* __restrict__ Filt)
{
    __shared__ short Plds[4][16][KSTR];   // per-wave bf16 P tile (C->A bounce)

    const int wg = blockIdx.x;            // 2048 = 8 b x 32 qt x 8 sp
    const int b = wg & 7;
    const int qt = (wg >> 3) & 31;
    const int sp = wg >> 8;
    const int tid = threadIdx.x;
    const int w = tid >> 6, lane = tid & 63, col = lane & 15, quad = lane >> 4;

    const float* Qb = Qg + (size_t)b * SDIM * DDIM;
    const int*   Mb = Mg + (size_t)b * SDIM;
    const short* Kb = Kbf + (size_t)b * SDIM * DDIM;
    const short* VTb = VTbf + (size_t)b * DDIM * SDIM;
    float* Ctxb  = Ctx  + (size_t)b * SDIM * DDIM;
    float* Filtb = Filt + (size_t)b * SDIM * SDIM;

    bf16x8 aq[2];
    {
        const float* qsrc = Qb + (size_t)(qt * 64 + w * 16 + col) * DDIM + quad * 8;
        #pragma unroll
        for (int c = 0; c < 2; ++c) {
            float4 f0 = *(const float4*)(qsrc + c * 32);
            float4 f1 = *(const float4*)(qsrc + c * 32 + 4);
            bf16x8 a;
            a[0]=f2bf(f0.x); a[1]=f2bf(f0.y); a[2]=f2bf(f0.z); a[3]=f2bf(f0.w);
            a[4]=f2bf(f1.x); a[5]=f2bf(f1.y); a[6]=f2bf(f1.z); a[7]=f2bf(f1.w);
            aq[c] = a;
        }
    }

    float invl[4];
    #pragma unroll
    for (int r = 0; r < 4; ++r)
        invl[r] = stats[b * SDIM + qt * 64 + w * 16 + quad * 4 + r];

    const int kb0 = sp * BPW * KBLK;
    f32x4 Oacc[4];
    #pragma unroll
    for (int dt = 0; dt < 4; ++dt) Oacc[dt] = (f32x4){0.f, 0.f, 0.f, 0.f};

    for (int kb = 0; kb < BPW; ++kb) {
        const int kbase = kb0 + kb * KBLK;

        // scores -> p -> (NT global store, bf16 LDS park)
        #pragma unroll
        for (int t = 0; t < 4; ++t) {
            const short* krow = Kb + (size_t)(kbase + t * 16 + col) * DDIM + quad * 8;
            f32x4 acc = {0.f, 0.f, 0.f, 0.f};
            #pragma unroll
            for (int c = 0; c < 2; ++c) {
                bf16x8 bk = *(const bf16x8*)(krow + c * 32);
                acc = __builtin_amdgcn_mfma_f32_16x16x32_bf16(aq[c], bk, acc, 0, 0, 0);
            }
            const int mk = Mb[kbase + t * 16 + col];
            #pragma unroll
            for (int r = 0; r < 4; ++r) {
                float p = mk ? 0.0f : __expf(acc[r] * SCALE) * invl[r];
                __builtin_nontemporal_store(
                    p, &Filtb[(size_t)(qt * 64 + w * 16 + quad * 4 + r) * SDIM + kbase + t * 16 + col]);
                Plds[w][quad * 4 + r][t * 16 + col] = f2bf(p);
            }
        }

        // O += P * V   (A from per-wave Plds; B-frag = 8 contiguous bf16 in VTbf)
        #pragma unroll
        for (int c = 0; c < 2; ++c) {
            bf16x8 ap = *(const bf16x8*)&Plds[w][col][c * 32 + quad * 8];
            #pragma unroll
            for (int dt = 0; dt < 4; ++dt) {
                const short* vrow = VTb + (size_t)(dt * 16 + col) * SDIM + kbase + c * 32 + quad * 8;
                bf16x8 bv = *(const bf16x8*)vrow;
                Oacc[dt] = __builtin_amdgcn_mfma_f32_16x16x32_bf16(ap, bv, Oacc[dt], 0, 0, 0);
            }
        }
    }

    // accumulate partial context (8-way contention across key-splits)
    #pragma unroll
    for (int dt = 0; dt < 4; ++dt) {
        #pragma unroll
        for (int r = 0; r < 4; ++r) {
            unsafeAtomicAdd(&Ctxb[(size_t)(qt * 64 + w * 16 + quad * 4 + r) * DDIM + dt * 16 + col],
                            Oacc[dt][r]);
        }
    }
}

extern "C" void kernel_launch(void* const* d_in, const int* in_sizes, int n_in,
                              void* d_out, int out_size, void* d_ws, size_t ws_size,
                              hipStream_t stream) {
    // setup_inputs order: key, query, value, query_attention_mask
    const float* Kg = (const float*)d_in[0];
    const float* Qg = (const float*)d_in[1];
    const float* Vg = (const float*)d_in[2];
    const int*   Mg = (const int*)d_in[3];
    float* Ctx  = (float*)d_out;                                   // [8,2048,64]
    float* Filt = (float*)d_out + (size_t)BATCH * SDIM * DDIM;     // [8,2048,2048]

    // workspace: Kbf 2 MB | VTbf 2 MB | part 512 KB | stats 64 KB
    short* Kbf  = (short*)d_ws;                                    // [8][2048][64] bf16
    short* VTbf = Kbf + (size_t)BATCH * SDIM * DDIM;               // [8][64][2048] bf16
    float* part  = (float*)(VTbf + (size_t)BATCH * DDIM * SDIM);   // [8][16384]
    float* stats = part + (size_t)KSPLIT * NROWS;                  // [16384]

    attn_prep<<<dim3(BATCH * NBLK), dim3(256), 0, stream>>>(Kg, Vg, Kbf, VTbf, Ctx);
    // 8 batches x 32 qtiles x 8 key-splits = 2048 WGs (sp = wg>>8 decode)
    attn_stats<<<dim3(BATCH * NBLK * KSPLIT), dim3(256), 0, stream>>>(Kbf, Qg, Mg, part);
    attn_merge<<<dim3(NROWS / 256), dim3(256), 0, stream>>>(part, stats);
    attn_emit<<<dim3(BATCH * NBLK * KSPLIT), dim3(256), 0, stream>>>(Kbf, VTbf, Qg, Mg, stats, Ctx, Filt);
}